// Round 4
// baseline (232.526 us; speedup 1.0000x reference)
//
#include <hip/hip_runtime.h>
#include <cstdint>
#include <cmath>

#define B_ 4
#define H_ 256
#define C_ 80
#define TX_ 256
#define TY_ 1024
#define NEGF (-1e9f)

// output layout (floats): o_en_ex [B,H,TY] | logp [B,TX,TY] | attn [B,TX,TY] | dr [B,TX]
#define OFF_LOGP (B_*H_*TY_)
#define OFF_ATTN (OFF_LOGP + B_*TX_*TY_)
#define OFF_DR   (OFF_ATTN + B_*TX_*TY_)

// __shfl_up(x,1) as pure VALU: DPP wave_shr:1 (ctrl 0x138); lane 0 gets NEGF.
__device__ __forceinline__ float dpp_shr1_negfill_f32(float x) {
  union { float f; int i; } u, o, r;
  u.f = x; o.f = NEGF;
  r.i = __builtin_amdgcn_update_dpp(o.i, u.i, 0x138, 0xf, 0xf, false);
  return r.f;
}

// ---------------------------------------------------------------------------
// R17: single fused persistent kernel.
//
// Evidence: across R13/R14/R15/R16, (total - k_dp) == ~100 us CONSTANT while
// k_dp varied 80..145 us.  Modeled k_logp ~6-15 us + k_epi ~3 us ->  up to
// ~80 us of inter-kernel launch/gap overhead.  Fix: one 256-block kernel
// (1 block/CU forced by 132KB LDS; grid == CU count -> co-resident), phases
// chained by device-scope atomic flags in workspace:
//   phase1: all blocks compute logp (verbatim R5 code); release done1[b].
//   phase2: blocks 0..3 acquire done1[b]==64; run R16 barrier-free
//           producer-consumer DP verbatim; release dp_done[b].
//   phase3: block bid handles 8 epilogue units of batch bid>>6 after
//           acquiring dp_done -- per-batch epilogue starts as soon as that
//           batch's DP finishes.
// Flags zeroed via hipMemsetAsync each replay (stale-flag re-poison trap).
// __hip_atomic_* AGENT scope provides cross-XCD visibility (wb/inv).
// DP math and backtrack bit-identical to R16 (passed).
// LDS: arena 96KB (phase1 tables+tile alias DP ring) + bits 32KB + dur 1KB.
// ---------------------------------------------------------------------------
#define POLL_FLAG(i)                                                     \
  { while (vflag[i] == 0u) __builtin_amdgcn_s_sleep(1);                  \
    asm volatile("" ::: "memory"); }

#define DP_CHUNK(SHBASE)                                                 \
  _Pragma("unroll")                                                      \
  for (int u = 0; u < 16; ++u) {                                         \
    float4 col = rr[u & 7];                                              \
    rr[u & 7] = (u < 8) ? pA[(u + 8) * 64 + lane]                        \
                        : pB[(u - 8) * 64 + lane];                       \
    float sh = dpp_shr1_negfill_f32(v3);                                 \
    float m0 = fmaxf(v0, sh);                                            \
    float m1 = fmaxf(v1, v0);                                            \
    float m2 = fmaxf(v2, v1);                                            \
    float m3 = fmaxf(v3, v2);                                            \
    w0 |= (__float_as_uint(v0 - m0) >> 31) << ((SHBASE) + u);            \
    w1 |= (__float_as_uint(v1 - m1) >> 31) << ((SHBASE) + u);            \
    w2 |= (__float_as_uint(v2 - m2) >> 31) << ((SHBASE) + u);            \
    w3 |= (__float_as_uint(v3 - m3) >> 31) << ((SHBASE) + u);            \
    v0 = col.x + m0;                                                     \
    v1 = col.y + m1;                                                     \
    v2 = col.z + m2;                                                     \
    v3 = col.w + m3;                                                     \
  }

__global__ __launch_bounds__(256, 1) void k_fused(
    const float* __restrict__ en, const float* __restrict__ mu,
    const float* __restrict__ ls, const float* __restrict__ y,
    const int* __restrict__ xlp, const int* __restrict__ ylp,
    float* __restrict__ oen, float* __restrict__ logp_out,
    float* __restrict__ attn,          // doubles as lpT scratch until phase 3
    float* __restrict__ dr_out,
    int* __restrict__ cum_ws, int* __restrict__ xt_ws,
    int* __restrict__ gflags)          // [0..3] done1 cnt, [4..7] dp_done
{
  const int bid = blockIdx.x;
  const int tid = threadIdx.x;

  __shared__ __align__(16) char     arena[96 * 1024];  // DP ring / ph1 tables
  __shared__ __align__(16) uint32_t bits[8192];        // 32 KB
  __shared__ __align__(16) uint32_t dur[TX_];          // 1 KB (ph3: row[])
  __shared__ uint32_t dflags[64];
  __shared__ int      dprog;

  float* lpT = attn;

  // ======================= phase 1: logp (all blocks) ======================
  {
    const int b  = bid >> 6;
    const int x0 = (bid & 63) * 4;
    double (*s_w)[C_]   = (double(*)[C_])(arena);
    double (*s_m1)[C_]  = (double(*)[C_])(arena + 2560);
    double (*s_wm2)[C_] = (double(*)[C_])(arena + 5120);
    double (*s_lsv)[C_] = (double(*)[C_])(arena + 7680);
    double* s_K  = (double*)(arena + 10240);
    double* s_t0 = (double*)(arena + 10272);
    float (*tile)[4] = (float(*)[4])(arena + 10304);   // [TY_][4], 16 KB

    for (int i = tid; i < 4 * C_; i += 256) {
      int xi = i / C_, c = i - xi * C_;
      double m = (double)mu[(b * C_ + c) * TX_ + x0 + xi];
      double l = (double)ls[(b * C_ + c) * TX_ + x0 + xi];
      double w = exp(-2.0 * l);
      s_w[xi][c]   = w;
      s_m1[xi][c]  = -2.0 * w * m;
      s_wm2[xi][c] = w * m * m;
      s_lsv[xi][c] = l;
    }
    __syncthreads();
    {
      int xi = tid >> 6, cc = tid & 63;
      double kp = (cc < C_) ? s_wm2[xi][cc] : 0.0;
      double tp = (cc < C_) ? s_lsv[xi][cc] : 0.0;
      if (cc + 64 < C_) { kp += s_wm2[xi][cc + 64]; tp += s_lsv[xi][cc + 64]; }
#pragma unroll
      for (int off = 32; off; off >>= 1) {
        kp += __shfl_down(kp, off);
        tp += __shfl_down(tp, off);
      }
      if (cc == 0) { s_K[xi] = kp; s_t0[xi] = -0.5 * (tp * (1.0 / C_)); }
    }
    __syncthreads();

    const int t0 = tid * 4;
    double acc[4][4];
#pragma unroll
    for (int xi = 0; xi < 4; ++xi)
#pragma unroll
      for (int k = 0; k < 4; ++k) acc[xi][k] = 0.0;

    const float4* yp = (const float4*)(y + (size_t)b * C_ * TY_) + tid;
#pragma unroll 4
    for (int c = 0; c < C_; ++c) {
      float4 yv = yp[c * (TY_ / 4)];
      double y0 = yv.x, y1 = yv.y, y2 = yv.z, y3 = yv.w;
#pragma unroll
      for (int xi = 0; xi < 4; ++xi) {
        double w = s_w[xi][c], m1 = s_m1[xi][c];
        double u0 = fma(w, y0, m1), u1 = fma(w, y1, m1);
        double u2 = fma(w, y2, m1), u3 = fma(w, y3, m1);
        acc[xi][0] = fma(u0, y0, acc[xi][0]);
        acc[xi][1] = fma(u1, y1, acc[xi][1]);
        acc[xi][2] = fma(u2, y2, acc[xi][2]);
        acc[xi][3] = fma(u3, y3, acc[xi][3]);
      }
    }

    const int xlen = xlp[b], ylen = ylp[b];
#pragma unroll
    for (int xi = 0; xi < 4; ++xi) {
      int x = x0 + xi;
      double c0 = s_t0[xi], K = s_K[xi];
      float r[4];
#pragma unroll
      for (int k = 0; k < 4; ++k)
        r[k] = (float)((acc[xi][k] + K) * (-0.5 / C_) + c0);
      *(float4*)&logp_out[((size_t)(b * TX_ + x)) * TY_ + t0] =
          make_float4(r[0], r[1], r[2], r[3]);
      bool xm = x < xlen;
#pragma unroll
      for (int k = 0; k < 4; ++k)
        tile[t0 + k][xi] = (xm && (t0 + k) < ylen) ? r[k] : NEGF;
    }
    __syncthreads();

    float* dst = lpT + (size_t)b * TY_ * TX_ + x0;
    const float4* tp = (const float4*)tile;
#pragma unroll
    for (int k = 0; k < 4; ++k) {
      int t = tid + 256 * k;
      *(float4*)&dst[(size_t)t * TX_] = tp[t];
    }
  }
  __threadfence();            // publish lpT writes device-wide
  __syncthreads();
  if (tid == 0)
    __hip_atomic_fetch_add(&gflags[bid >> 6], 1, __ATOMIC_RELEASE,
                           __HIP_MEMORY_SCOPE_AGENT);

  // ======================= phase 2: DP (blocks 0..3) =======================
  if (bid < B_) {
    const int b = bid;
    if (tid == 0) {
      while (__hip_atomic_load(&gflags[b], __ATOMIC_ACQUIRE,
                               __HIP_MEMORY_SCOPE_AGENT) < 64)
        __builtin_amdgcn_s_sleep(8);
    }
    __syncthreads();

    const int lane = tid & 63;
    const int w = tid >> 6;               // 0 = consumer, 1..3 = producers
    float* ring = (float*)arena;          // 6 slots x 16 rows x 256 = 96 KB
    const float4* gb4   = (const float4*)(lpT + (size_t)b * TY_ * TX_);
    const float4* ring4 = (const float4*)ring;

    const int ylen = ylp[b];
    const int nch  = ((ylen + 31) >> 5) << 1;   // even # of 16-row chunks

    if (tid < 64) dflags[tid] = 0u;
    if (tid == 0) dprog = -1;
    __syncthreads();

    if (w == 0) {
      // ---------------- consumer: pure LDS + VALU DP ----------------
      volatile uint32_t* vflag = dflags;
      volatile int*      vprog = &dprog;
      POLL_FLAG(0);
      float4 rr[8];
#pragma unroll
      for (int i = 0; i < 8; ++i) rr[i] = ring4[i * 64 + lane];

      float v0 = (lane == 0) ? 0.0f : NEGF;
      float v1 = NEGF, v2 = NEGF, v3 = NEGF;
      uint32_t w0 = 0, w1 = 0, w2 = 0, w3 = 0;
      int sA = 0, sB = 1;
      const float4* pA;
      const float4* pB;

      for (int cp = 0; cp < nch; cp += 2) {
        { int nf = (cp + 1 < nch) ? cp + 1 : nch - 1; POLL_FLAG(nf); }
        pA = ring4 + sA * 1024; pB = ring4 + sB * 1024;
        DP_CHUNK(0)
        asm volatile("" ::: "memory");
        *vprog = cp;
        sA = sB; sB = (sB == 5) ? 0 : sB + 1;

        { int nf = (cp + 2 < nch) ? cp + 2 : nch - 1; POLL_FLAG(nf); }
        pA = ring4 + sA * 1024; pB = ring4 + sB * 1024;
        DP_CHUNK(16)
        *(uint4*)&bits[(cp >> 1) * 256 + 4 * lane] = make_uint4(w0, w1, w2, w3);
        w0 = w1 = w2 = w3 = 0;
        asm volatile("" ::: "memory");
        *vprog = cp + 1;
        sA = sB; sB = (sB == 5) ? 0 : sB + 1;
      }
    } else {
      // ---------------- producers: global -> reg -> LDS ring ----------------
      const int p = w - 1;                  // 0..2, chunks c ≡ p (mod 3)
      volatile int*      vprog = &dprog;
      volatile uint32_t* vflag = dflags;
      for (int c = p; c < nch; c += 3) {
        const int need = c - 6;
        while (*vprog < need) __builtin_amdgcn_s_sleep(8);
        asm volatile("" ::: "memory");
        const float4* src = gb4 + (size_t)(c * 16) * 64 + lane;
        float4 tmp[16];
#pragma unroll
        for (int r = 0; r < 16; ++r) tmp[r] = src[r * 64];
        float4* dst = (float4*)&ring[(c % 6) * 4096] + lane;
#pragma unroll
        for (int r = 0; r < 16; ++r) dst[r * 64] = tmp[r];
        asm volatile("s_waitcnt lgkmcnt(0)" ::: "memory");
        vflag[c] = 1u;
      }
    }

    __syncthreads();
    dur[tid] = 0;
    __syncthreads();

    const int xlen = xlp[b];
    if (tid == 0) {
      int idx = xlen - 1;
      int t = ylen - 1;
      while (t >= 0) {
        if (idx == 0) { dur[0] = (uint32_t)(t + 1); break; }
        int ww = t >> 5, rrm = t & 31;
        uint32_t wd = bits[ww * 256 + idx];
        wd &= (rrm == 31) ? 0xffffffffu : ((1u << (rrm + 1)) - 1u);
        while (wd == 0 && ww > 0) { --ww; wd = bits[ww * 256 + idx]; }
        if (wd == 0) { dur[idx] = (uint32_t)(t + 1); break; }
        int bitpos = 31 - __builtin_clz(wd);
        int tp = (ww << 5) | bitpos;
        dur[idx] = (uint32_t)(t - tp + 1);
        --idx;
        t = tp - 1;
      }
    }
    __syncthreads();

    if (w == 0) {
      // wave-wide inclusive scan of durations -> cum, dr, t->x scatter map
      uint32_t d0 = dur[4 * lane], d1 = dur[4 * lane + 1];
      uint32_t d2 = dur[4 * lane + 2], d3 = dur[4 * lane + 3];
      uint32_t own = d0 + d1 + d2 + d3;
      uint32_t s = own;
#pragma unroll
      for (int off = 1; off < 64; off <<= 1) {
        uint32_t n = __shfl_up(s, off);
        if (lane >= off) s += n;
      }
      uint32_t base = s - own;
      uint32_t c0 = base + d0, c1 = c0 + d1, c2 = c1 + d2, c3 = c2 + d3;
      int x = 4 * lane;
      cum_ws[b * TX_ + x]     = (int)c0;
      cum_ws[b * TX_ + x + 1] = (int)c1;
      cum_ws[b * TX_ + x + 2] = (int)c2;
      cum_ws[b * TX_ + x + 3] = (int)c3;
      dr_out[b * TX_ + x]     = (float)d0;
      dr_out[b * TX_ + x + 1] = (float)d1;
      dr_out[b * TX_ + x + 2] = (float)d2;
      dr_out[b * TX_ + x + 3] = (float)d3;
      int* xt = xt_ws + b * TY_;
      for (uint32_t t = c0 - d0; t < c0; ++t) xt[t] = x;
      for (uint32_t t = c1 - d1; t < c1; ++t) xt[t] = x + 1;
      for (uint32_t t = c2 - d2; t < c2; ++t) xt[t] = x + 2;
      for (uint32_t t = c3 - d3; t < c3; ++t) xt[t] = x + 3;
    }
    __threadfence();          // publish cum/xt/dr device-wide
    __syncthreads();
    if (tid == 0)
      __hip_atomic_store(&gflags[B_ + b], 1, __ATOMIC_RELEASE,
                         __HIP_MEMORY_SCOPE_AGENT);
  }

  // ================= phase 3: epilogue (8 units per block) =================
  {
    const int b3 = bid >> 6;
    if (tid == 0) {
      while (__hip_atomic_load(&gflags[B_ + b3], __ATOMIC_ACQUIRE,
                               __HIP_MEMORY_SCOPE_AGENT) == 0)
        __builtin_amdgcn_s_sleep(32);
    }
    __syncthreads();

    float* row = (float*)dur;            // 256 floats, DP use finished
    const int ylen = ylp[b3];
    const int t0 = tid * 4;
#pragma unroll
    for (int k = 0; k < 8; ++k) {
      const int r = (bid & 63) * 8 + k;  // 0..511 within batch b3
      if (r < TX_) {
        const int x = r;
        int hi = cum_ws[b3 * TX_ + x];
        int lo = (x > 0) ? cum_ws[b3 * TX_ + x - 1] : 0;
        float4 v;
        v.x = (t0     >= lo && t0     < hi) ? 1.f : 0.f;
        v.y = (t0 + 1 >= lo && t0 + 1 < hi) ? 1.f : 0.f;
        v.z = (t0 + 2 >= lo && t0 + 2 < hi) ? 1.f : 0.f;
        v.w = (t0 + 3 >= lo && t0 + 3 < hi) ? 1.f : 0.f;
        *(float4*)&attn[((size_t)(b3 * TX_ + x)) * TY_ + t0] = v;
      } else {
        const int h = r - TX_;
        __syncthreads();
        row[tid] = en[((size_t)(b3 * H_ + h)) * TX_ + tid];
        __syncthreads();
        int4 xi = *(const int4*)&xt_ws[b3 * TY_ + t0];
        float4 v;
        v.x = (t0     < ylen) ? row[xi.x & (TX_ - 1)] : 0.f;
        v.y = (t0 + 1 < ylen) ? row[xi.y & (TX_ - 1)] : 0.f;
        v.z = (t0 + 2 < ylen) ? row[xi.z & (TX_ - 1)] : 0.f;
        v.w = (t0 + 3 < ylen) ? row[xi.w & (TX_ - 1)] : 0.f;
        *(float4*)&oen[((size_t)(b3 * H_ + h)) * TY_ + t0] = v;
      }
    }
  }
}

extern "C" void kernel_launch(void* const* d_in, const int* in_sizes, int n_in,
                              void* d_out, int out_size, void* d_ws, size_t ws_size,
                              hipStream_t stream)
{
  const float* en = (const float*)d_in[0];
  const float* mu = (const float*)d_in[1];
  const float* ls = (const float*)d_in[2];
  const float* y  = (const float*)d_in[3];
  const int*   xl = (const int*)d_in[4];
  const int*   yl = (const int*)d_in[5];

  float* out  = (float*)d_out;
  float* oen  = out;             // [B,H,TY]
  float* logp = out + OFF_LOGP;  // [B,TX,TY]
  float* attn = out + OFF_ATTN;  // [B,TX,TY] (doubles as lpT scratch first)
  float* dr   = out + OFF_DR;    // [B,TX]

  int* cum    = (int*)d_ws;              // B*TX ints
  int* xt     = cum + B_ * TX_;          // B*TY ints
  int* gflags = xt + B_ * TY_;           // 8 ints: done1[4], dp_done[4]

  hipMemsetAsync(gflags, 0, 8 * sizeof(int), stream);
  k_fused<<<dim3(256), 256, 0, stream>>>(en, mu, ls, y, xl, yl,
                                         oen, logp, attn, dr, cum, xt, gflags);
}

// Round 5
// 166.675 us; speedup vs baseline: 1.3951x; 1.3951x over previous
//
#include <hip/hip_runtime.h>
#include <cstdint>
#include <cmath>

#define B_ 4
#define H_ 256
#define C_ 80
#define TX_ 256
#define TY_ 1024
#define NEGF (-1e9f)

// output layout (floats): o_en_ex [B,H,TY] | logp [B,TX,TY] | attn [B,TX,TY] | dr [B,TX]
#define OFF_LOGP (B_*H_*TY_)
#define OFF_ATTN (OFF_LOGP + B_*TX_*TY_)
#define OFF_DR   (OFF_ATTN + B_*TX_*TY_)

// __shfl_up(x,1) as pure VALU: DPP wave_shr:1 (ctrl 0x138); lane 0 gets NEGF.
__device__ __forceinline__ float dpp_shr1_negfill_f32(float x) {
  union { float f; int i; } u, o, r;
  u.f = x; o.f = NEGF;
  r.i = __builtin_amdgcn_update_dpp(o.i, u.i, 0x138, 0xf, 0xf, false);
  return r.f;
}

// ---------------------------------------------------------------------------
// Kernel A (R18): logp, restructured for occupancy; math BIT-IDENTICAL.
//
// R17 post-mortem: fused-kernel timing isolated logp at ~75-100 us (the
// constant ~100us residual of R13..R16 was never launch gaps).  Cause: grid
// 256 blocks = 1 block/CU = 1 wave/SIMD -> every ds_read->f64-FMA dependency
// pays full ~120cyc LDS latency, every y-load ~200cyc L2 latency, no TLP.
// Fix: block = 4 x-columns x 256 t's, ONE WAVE PER X-COLUMN (wave w owns
// x0+w; its 64 lanes own 4 t's each).  Grid (TX/4, TY/256, B) = 1024 blocks
// -> 4 blocks/CU = 4 waves/SIMD.  (w,m1) packed as double2 -> 1 ds_read_b128
// per (xi,c).  Per-thread c-loop order, FMA chain, and the K/t0 shuffle
// reduction are verbatim -> logp/lpT outputs bit-identical to the R3 build
// that passes (absmax 0.0078125); DP tie-breaks cannot flip.
// LDS: s_wm 5.1KB + s_wm2/s_lsv 5.1KB + tile 4KB + K/t0 = ~15KB.
// ---------------------------------------------------------------------------
__global__ __launch_bounds__(256) void k_logp(
    const float* __restrict__ mu, const float* __restrict__ ls,
    const float* __restrict__ y, const int* __restrict__ xlp,
    const int* __restrict__ ylp, float* __restrict__ logp_out,
    float* __restrict__ lpT)
{
  const int b  = blockIdx.z;
  const int tq = blockIdx.y;              // t-quarter: rows tq*256 .. tq*256+255
  const int x0 = blockIdx.x * 4;
  const int tid = threadIdx.x;
  const int lane = tid & 63;
  const int xi = tid >> 6;                // wave id == x-column index

  __shared__ double2 s_wm[4][C_];         // (w, -2*w*mu) packed -> ds_read_b128
  __shared__ double  s_wm2[4][C_];
  __shared__ double  s_lsv[4][C_];
  __shared__ double  s_K[4];
  __shared__ double  s_t0[4];
  __shared__ float   tile[256][4];        // [t_local][x] transpose staging

  for (int i = tid; i < 4 * C_; i += 256) {
    int xj = i / C_, c = i - xj * C_;
    double m = (double)mu[(b * C_ + c) * TX_ + x0 + xj];
    double l = (double)ls[(b * C_ + c) * TX_ + x0 + xj];
    double w = exp(-2.0 * l);
    s_wm[xj][c]  = make_double2(w, -2.0 * w * m);
    s_wm2[xj][c] = w * m * m;
    s_lsv[xj][c] = l;
  }
  __syncthreads();
  {
    int cc = lane;
    double kp = (cc < C_) ? s_wm2[xi][cc] : 0.0;
    double tp = (cc < C_) ? s_lsv[xi][cc] : 0.0;
    if (cc + 64 < C_) { kp += s_wm2[xi][cc + 64]; tp += s_lsv[xi][cc + 64]; }
#pragma unroll
    for (int off = 32; off; off >>= 1) {
      kp += __shfl_down(kp, off);
      tp += __shfl_down(tp, off);
    }
    if (cc == 0) { s_K[xi] = kp; s_t0[xi] = -0.5 * (tp * (1.0 / C_)); }
  }
  __syncthreads();

  // each thread: x = x0+xi, t = tq*256 + lane*4 .. +3
  double acc[4];
#pragma unroll
  for (int k = 0; k < 4; ++k) acc[k] = 0.0;

  const float4* yp = (const float4*)(y + (size_t)b * C_ * TY_ + tq * 256) + lane;
#pragma unroll 4
  for (int c = 0; c < C_; ++c) {
    float4 yv = yp[c * (TY_ / 4)];
    double y0 = yv.x, y1 = yv.y, y2 = yv.z, y3 = yv.w;
    double2 wm = s_wm[xi][c];
    double w = wm.x, m1 = wm.y;
    double u0 = fma(w, y0, m1), u1 = fma(w, y1, m1);
    double u2 = fma(w, y2, m1), u3 = fma(w, y3, m1);
    acc[0] = fma(u0, y0, acc[0]);
    acc[1] = fma(u1, y1, acc[1]);
    acc[2] = fma(u2, y2, acc[2]);
    acc[3] = fma(u3, y3, acc[3]);
  }

  const int xlen = xlp[b], ylen = ylp[b];
  const int x  = x0 + xi;
  const int t0 = tq * 256 + lane * 4;
  {
    double c0 = s_t0[xi], K = s_K[xi];
    float r[4];
#pragma unroll
    for (int k = 0; k < 4; ++k)
      r[k] = (float)((acc[k] + K) * (-0.5 / C_) + c0);
    *(float4*)&logp_out[((size_t)(b * TX_ + x)) * TY_ + t0] =
        make_float4(r[0], r[1], r[2], r[3]);
    bool xm = x < xlen;
#pragma unroll
    for (int k = 0; k < 4; ++k)
      tile[lane * 4 + k][xi] = (xm && (t0 + k) < ylen) ? r[k] : NEGF;
  }
  __syncthreads();

  // lpT[b][t][x0..x0+3] for t in this quarter; thread tid handles t_local=tid
  float* dst = lpT + (size_t)b * TY_ * TX_ + x0;
  const float4* tp = (const float4*)tile;
  *(float4*)&dst[(size_t)(tq * 256 + tid) * TX_] = tp[tid];
}

// ---------------------------------------------------------------------------
// Kernel B (R16, unchanged): barrier-free producer-consumer Viterbi DP.
// Sync = LDS flags + consumer progress counter; producers free-run up to 6
// chunks ahead (6-slot x 16-row ring, 96KB).  Validated R3: 79.6us, passes.
// ---------------------------------------------------------------------------
#define POLL_FLAG(i)                                                     \
  { while (vflag[i] == 0u) __builtin_amdgcn_s_sleep(1);                  \
    asm volatile("" ::: "memory"); }

#define DP_CHUNK(SHBASE)                                                 \
  _Pragma("unroll")                                                      \
  for (int u = 0; u < 16; ++u) {                                         \
    float4 col = rr[u & 7];                                              \
    rr[u & 7] = (u < 8) ? pA[(u + 8) * 64 + lane]                        \
                        : pB[(u - 8) * 64 + lane];                       \
    float sh = dpp_shr1_negfill_f32(v3);                                 \
    float m0 = fmaxf(v0, sh);                                            \
    float m1 = fmaxf(v1, v0);                                            \
    float m2 = fmaxf(v2, v1);                                            \
    float m3 = fmaxf(v3, v2);                                            \
    w0 |= (__float_as_uint(v0 - m0) >> 31) << ((SHBASE) + u);            \
    w1 |= (__float_as_uint(v1 - m1) >> 31) << ((SHBASE) + u);            \
    w2 |= (__float_as_uint(v2 - m2) >> 31) << ((SHBASE) + u);            \
    w3 |= (__float_as_uint(v3 - m3) >> 31) << ((SHBASE) + u);            \
    v0 = col.x + m0;                                                     \
    v1 = col.y + m1;                                                     \
    v2 = col.z + m2;                                                     \
    v3 = col.w + m3;                                                     \
  }

__global__ __launch_bounds__(256, 1) void k_dp(
    const float* __restrict__ lpT, const int* __restrict__ xlp,
    const int* __restrict__ ylp, float* __restrict__ dr_out,
    int* __restrict__ cum_ws, int* __restrict__ xt_ws)
{
  const int b = blockIdx.x;
  const int tid = threadIdx.x;
  const int lane = tid & 63;
  const int w = tid >> 6;                 // 0 = consumer, 1..3 = producers
  __shared__ __align__(16) float    ring[6 * 16 * 256];  // 96 KB, 6 slots
  __shared__ __align__(16) uint32_t bits[8192];          // 32 KB
  __shared__ __align__(16) uint32_t dur[TX_];            // 1 KB
  __shared__ uint32_t flags[64];
  __shared__ int      prog;

  const float4* gb4   = (const float4*)(lpT + (size_t)b * TY_ * TX_);
  const float4* ring4 = (const float4*)ring;

  const int ylen = ylp[b];
  const int nch  = ((ylen + 31) >> 5) << 1;   // even # of 16-row chunks, 32..64

  if (tid < 64) flags[tid] = 0u;
  if (tid == 0) prog = -1;
  __syncthreads();

  if (w == 0) {
    // ---------------- consumer: pure LDS + VALU DP ----------------
    volatile uint32_t* vflag = flags;
    volatile int*      vprog = &prog;
    POLL_FLAG(0);
    float4 rr[8];
#pragma unroll
    for (int i = 0; i < 8; ++i) rr[i] = ring4[i * 64 + lane];  // slot0 rows 0..7

    float v0 = (lane == 0) ? 0.0f : NEGF;
    float v1 = NEGF, v2 = NEGF, v3 = NEGF;
    uint32_t w0 = 0, w1 = 0, w2 = 0, w3 = 0;
    int sA = 0, sB = 1;
    const float4* pA;
    const float4* pB;

    for (int cp = 0; cp < nch; cp += 2) {
      { int nf = (cp + 1 < nch) ? cp + 1 : nch - 1; POLL_FLAG(nf); }
      pA = ring4 + sA * 1024; pB = ring4 + sB * 1024;
      DP_CHUNK(0)
      asm volatile("" ::: "memory");
      *vprog = cp;
      sA = sB; sB = (sB == 5) ? 0 : sB + 1;

      { int nf = (cp + 2 < nch) ? cp + 2 : nch - 1; POLL_FLAG(nf); }
      pA = ring4 + sA * 1024; pB = ring4 + sB * 1024;
      DP_CHUNK(16)
      *(uint4*)&bits[(cp >> 1) * 256 + 4 * lane] = make_uint4(w0, w1, w2, w3);
      w0 = w1 = w2 = w3 = 0;
      asm volatile("" ::: "memory");
      *vprog = cp + 1;
      sA = sB; sB = (sB == 5) ? 0 : sB + 1;
    }
  } else {
    // ---------------- producers: global -> reg -> LDS ring ----------------
    const int p = w - 1;                  // 0..2, handles chunks c ≡ p (mod 3)
    volatile int*      vprog = &prog;
    volatile uint32_t* vflag = flags;
    for (int c = p; c < nch; c += 3) {
      const int need = c - 6;             // slot tenant c-6 must be consumed
      while (*vprog < need) __builtin_amdgcn_s_sleep(8);
      asm volatile("" ::: "memory");
      const float4* src = gb4 + (size_t)(c * 16) * 64 + lane;
      float4 tmp[16];
#pragma unroll
      for (int r = 0; r < 16; ++r) tmp[r] = src[r * 64];
      float4* dst = (float4*)&ring[(c % 6) * 4096] + lane;
#pragma unroll
      for (int r = 0; r < 16; ++r) dst[r * 64] = tmp[r];
      asm volatile("s_waitcnt lgkmcnt(0)" ::: "memory");
      vflag[c] = 1u;
    }
  }

  __syncthreads();
  dur[tid] = 0;
  __syncthreads();

  const int xlen = xlp[b];
  if (tid == 0) {
    int idx = xlen - 1;
    int t = ylen - 1;
    while (t >= 0) {
      if (idx == 0) { dur[0] = (uint32_t)(t + 1); break; }
      int ww = t >> 5, rrm = t & 31;
      uint32_t wd = bits[ww * 256 + idx];
      wd &= (rrm == 31) ? 0xffffffffu : ((1u << (rrm + 1)) - 1u);
      while (wd == 0 && ww > 0) { --ww; wd = bits[ww * 256 + idx]; }
      if (wd == 0) { dur[idx] = (uint32_t)(t + 1); break; }
      int bitpos = 31 - __builtin_clz(wd);
      int tp = (ww << 5) | bitpos;       // step where diag fires -> decrement
      dur[idx] = (uint32_t)(t - tp + 1); // first visit of idx -> plain store
      --idx;
      t = tp - 1;
    }
  }
  __syncthreads();

  if (w == 0) {
    // wave-wide inclusive scan of durations -> cum, dr, and t->x scatter map
    uint32_t d0 = dur[4 * lane], d1 = dur[4 * lane + 1];
    uint32_t d2 = dur[4 * lane + 2], d3 = dur[4 * lane + 3];
    uint32_t own = d0 + d1 + d2 + d3;
    uint32_t s = own;
#pragma unroll
    for (int off = 1; off < 64; off <<= 1) {
      uint32_t n = __shfl_up(s, off);
      if (lane >= off) s += n;
    }
    uint32_t base = s - own;
    uint32_t c0 = base + d0, c1 = c0 + d1, c2 = c1 + d2, c3 = c2 + d3;
    int x = 4 * lane;
    cum_ws[b * TX_ + x]     = (int)c0;
    cum_ws[b * TX_ + x + 1] = (int)c1;
    cum_ws[b * TX_ + x + 2] = (int)c2;
    cum_ws[b * TX_ + x + 3] = (int)c3;
    dr_out[b * TX_ + x]     = (float)d0;
    dr_out[b * TX_ + x + 1] = (float)d1;
    dr_out[b * TX_ + x + 2] = (float)d2;
    dr_out[b * TX_ + x + 3] = (float)d3;
    int* xt = xt_ws + b * TY_;
    for (uint32_t t = c0 - d0; t < c0; ++t) xt[t] = x;
    for (uint32_t t = c1 - d1; t < c1; ++t) xt[t] = x + 1;
    for (uint32_t t = c2 - d2; t < c2; ++t) xt[t] = x + 2;
    for (uint32_t t = c3 - d3; t < c3; ++t) xt[t] = x + 3;
  }
}

// ---------------------------------------------------------------------------
// Kernel C (fused epilogue): blocks [0,TX) write attn rows from cum;
// blocks [TX,TX+H) gather o_en_ex[b,h,t] = t<ylen ? en[b,h,xt[b,t]] : 0.
// ---------------------------------------------------------------------------
__global__ __launch_bounds__(256) void k_epi(
    const int* __restrict__ cum_ws, const int* __restrict__ xt_ws,
    const float* __restrict__ en, const int* __restrict__ ylp,
    float* __restrict__ attn, float* __restrict__ oen)
{
  const int b = blockIdx.y, bx = blockIdx.x, tid = threadIdx.x;
  __shared__ float row[TX_];
  if (bx < TX_) {
    const int x = bx;
    int hi = cum_ws[b * TX_ + x];
    int lo = (x > 0) ? cum_ws[b * TX_ + x - 1] : 0;
    int t0 = tid * 4;
    float4 v;
    v.x = (t0     >= lo && t0     < hi) ? 1.f : 0.f;
    v.y = (t0 + 1 >= lo && t0 + 1 < hi) ? 1.f : 0.f;
    v.z = (t0 + 2 >= lo && t0 + 2 < hi) ? 1.f : 0.f;
    v.w = (t0 + 3 >= lo && t0 + 3 < hi) ? 1.f : 0.f;
    *(float4*)&attn[((size_t)(b * TX_ + x)) * TY_ + t0] = v;
  } else {
    const int h = bx - TX_;
    row[tid] = en[((size_t)(b * H_ + h)) * TX_ + tid];
    __syncthreads();
    const int ylen = ylp[b];
    int t0 = tid * 4;
    int4 xi = *(const int4*)&xt_ws[b * TY_ + t0];
    float4 v;
    v.x = (t0     < ylen) ? row[xi.x & (TX_ - 1)] : 0.f;
    v.y = (t0 + 1 < ylen) ? row[xi.y & (TX_ - 1)] : 0.f;
    v.z = (t0 + 2 < ylen) ? row[xi.z & (TX_ - 1)] : 0.f;
    v.w = (t0 + 3 < ylen) ? row[xi.w & (TX_ - 1)] : 0.f;
    *(float4*)&oen[((size_t)(b * H_ + h)) * TY_ + t0] = v;
  }
}

extern "C" void kernel_launch(void* const* d_in, const int* in_sizes, int n_in,
                              void* d_out, int out_size, void* d_ws, size_t ws_size,
                              hipStream_t stream)
{
  const float* en = (const float*)d_in[0];
  const float* mu = (const float*)d_in[1];
  const float* ls = (const float*)d_in[2];
  const float* y  = (const float*)d_in[3];
  const int*   xl = (const int*)d_in[4];
  const int*   yl = (const int*)d_in[5];

  float* out  = (float*)d_out;
  float* oen  = out;             // [B,H,TY]
  float* logp = out + OFF_LOGP;  // [B,TX,TY]
  float* attn = out + OFF_ATTN;  // [B,TX,TY] (doubles as lpT scratch first)
  float* dr   = out + OFF_DR;    // [B,TX]

  int* cum = (int*)d_ws;               // B*TX ints
  int* xt  = cum + B_ * TX_;           // B*TY ints

  k_logp<<<dim3(TX_ / 4, TY_ / 256, B_), 256, 0, stream>>>(mu, ls, y, xl, yl, logp, attn);
  k_dp  <<<B_,                           256, 0, stream>>>(attn, xl, yl, dr, cum, xt);
  k_epi <<<dim3(TX_ + H_, B_),           256, 0, stream>>>(cum, xt, en, yl, attn, oen);
}